// Round 5
// baseline (75.004 us; speedup 1.0000x reference)
//
#include <hip/hip_runtime.h>

#define BB 16
#define NN 2048
#define NFF 512
#define DD 4

#define ROWS 64        // K-rows per gemv block (4 waves x 16 rows)
#define WR 16          // rows per wave
#define YINT 32        // 32*64 = 2048 Wint rows
#define YTOT 40        // + 8*64 = 512 Wff rows
#define JC   128       // columns per x-block (64 lanes x 2 cols)

// ---------------- Kernel 1: elementwise pre-pass ----------------
// X = sigmoid((V-1-th)*5) -> out_X ; T[b,i] = sum_d Xd*(1+0.95*stp-0.3*Xd) -> ws
// Per-block partial sums for the 4 per-batch scalars:
//   blocks [0,128):   p0 = sum T*xpre_int, p1 = sum T*Xd0   (8 blocks/batch)
//   blocks [128,160): p0 = sum FF*xpre_ff, p1 = sum FF*FF   (2 blocks/batch)
// Block 0 also zeroes the 16 per-column counters used by snn_gemv's tail.
__global__ __launch_bounds__(256) void snn_pre(
    const float* __restrict__ FF, const float* __restrict__ V,
    const float* __restrict__ th, const float* __restrict__ Xbuf,
    const float* __restrict__ stp, const float* __restrict__ xpre_int,
    const float* __restrict__ xpre_ff,
    float* __restrict__ out_X, float* __restrict__ T,
    float* __restrict__ scal_part, unsigned int* __restrict__ cnt)
{
    __shared__ float red[8];
    int idx = blockIdx.x * 256 + threadIdx.x;
    if (blockIdx.x == 0 && threadIdx.x < 16) cnt[threadIdx.x] = 0u;
    float p0, p1;
    if (idx < BB * NN) {
        float v = V[idx], t = th[idx];
        float x = 1.f / (1.f + expf(-(v - 1.f - t) * 5.f));
        out_X[idx] = x;
        float xd0 = Xbuf[idx];
        float acc = 0.f;
        #pragma unroll
        for (int d = 0; d < DD; ++d) {
            float xd = Xbuf[d * BB * NN + idx];
            float s  = stp[d * BB * NN + idx];
            acc += xd * (1.f + 0.95f * s - 0.3f * xd);
        }
        T[idx] = acc;
        p0 = acc * xpre_int[idx];
        p1 = acc * xd0;
    } else {
        int k = idx - BB * NN;
        float f = FF[k];
        p0 = f * xpre_ff[k];
        p1 = f * f;
    }
    #pragma unroll
    for (int o = 32; o; o >>= 1) { p0 += __shfl_xor(p0, o); p1 += __shfl_xor(p1, o); }
    int w = threadIdx.x >> 6;
    if ((threadIdx.x & 63) == 0) { red[w * 2] = p0; red[w * 2 + 1] = p1; }
    __syncthreads();
    if (threadIdx.x == 0) {
        scal_part[blockIdx.x * 2]     = red[0] + red[2] + red[4] + red[6];
        scal_part[blockIdx.x * 2 + 1] = red[1] + red[3] + red[5] + red[7];
    }
}

// ---------------- Kernel 2: split-K GEMV + fused tail finalize ----------------
// part[y][b][j] = sum_{i in y's 64 rows} OP[b,i]*W[i,j];  y<32: Wint/T, else Wff/FF.
// The 40th block to finish a given x-column performs the post pass for those
// 128 columns (reduce partials + rank-1 scalar terms + membrane update).
__global__ __launch_bounds__(256, 2) void snn_gemv(
    const float* __restrict__ Wint, const float* __restrict__ Wff,
    const float* __restrict__ T, const float* __restrict__ FF,
    const float* __restrict__ V, const float* __restrict__ xpost,
    const float* __restrict__ scal_part, const float* __restrict__ out_X,
    float* __restrict__ out_V, float* __restrict__ part,
    unsigned int* __restrict__ cnt)
{
    __shared__ float c_lds[ROWS * BB];           // 4 KB  [row][b]
    __shared__ float red[2 * 2 * BB * 64];       // 16 KB [buf][r=2b+c][lane]
    __shared__ unsigned int tail_flag;
    __shared__ float csum[4 * BB];
    int y = blockIdx.y;
    const float* Wm; const float* OP; int i0, opstride;
    if (y < YINT) { Wm = Wint; OP = T;  i0 = y * ROWS;          opstride = NN;  }
    else          { Wm = Wff;  OP = FF; i0 = (y - YINT) * ROWS; opstride = NFF; }

    int t = threadIdx.x;
    #pragma unroll
    for (int k = 0; k < ROWS * BB / 256; ++k) {
        int e = k * 256 + t;
        int row = e >> 4, b = e & 15;
        c_lds[e] = OP[b * opstride + i0 + row];
    }
    __syncthreads();

    int w = t >> 6, l = t & 63;
    int j0 = blockIdx.x * JC + l * 2;
    float2 acc[BB];
    #pragma unroll
    for (int b = 0; b < BB; ++b) acc[b] = make_float2(0.f, 0.f);

    const float* wp = Wm + (size_t)(i0 + w * WR) * NN + j0;
    float2 buf[WR];
    #pragma unroll
    for (int r = 0; r < WR; ++r) buf[r] = *(const float2*)(wp + (size_t)r * NN);

    #pragma unroll
    for (int r = 0; r < WR; ++r) {
        const float4* cb = (const float4*)&c_lds[(w * WR + r) * BB];
        float4 c0 = cb[0], c1 = cb[1], c2 = cb[2], c3 = cb[3];
        float2 wv = buf[r];
#define FMA2(b, cc) acc[b].x += (cc) * wv.x; acc[b].y += (cc) * wv.y;
        FMA2(0,  c0.x) FMA2(1,  c0.y) FMA2(2,  c0.z) FMA2(3,  c0.w)
        FMA2(4,  c1.x) FMA2(5,  c1.y) FMA2(6,  c1.z) FMA2(7,  c1.w)
        FMA2(8,  c2.x) FMA2(9,  c2.y) FMA2(10, c2.z) FMA2(11, c2.w)
        FMA2(12, c3.x) FMA2(13, c3.y) FMA2(14, c3.z) FMA2(15, c3.w)
#undef FMA2
    }

    // tree-reduce the 4 waves' partials: [r][lane], conflict-free b32
    if (w >= 2) {
        float* rb = &red[(w - 2) * 2 * BB * 64];
        #pragma unroll
        for (int b = 0; b < BB; ++b) {
            rb[(2 * b) * 64 + l]     = acc[b].x;
            rb[(2 * b + 1) * 64 + l] = acc[b].y;
        }
    }
    __syncthreads();
    if (w < 2) {
        const float* rb = &red[w * 2 * BB * 64];
        #pragma unroll
        for (int b = 0; b < BB; ++b) {
            acc[b].x += rb[(2 * b) * 64 + l];
            acc[b].y += rb[(2 * b + 1) * 64 + l];
        }
    }
    __syncthreads();
    if (w == 1) {
        #pragma unroll
        for (int b = 0; b < BB; ++b) {
            red[(2 * b) * 64 + l]     = acc[b].x;
            red[(2 * b + 1) * 64 + l] = acc[b].y;
        }
    }
    __syncthreads();
    if (w == 0) {
        float* pp = part + (size_t)y * (BB * NN) + j0;
        #pragma unroll
        for (int b = 0; b < BB; ++b) {
            acc[b].x += red[(2 * b) * 64 + l];
            acc[b].y += red[(2 * b + 1) * 64 + l];
            *(float2*)(pp + (size_t)b * NN) = acc[b];
        }
    }

    // ---- last-block-per-column tail ----
    __syncthreads();                 // drains wave 0's part stores (vmcnt(0))
    __threadfence();                 // device-scope release (L2 writeback)
    if (t == 0) {
        unsigned int old = atomicAdd(&cnt[blockIdx.x], 1u);
        tail_flag = (old == YTOT - 1) ? 1u : 0u;
    }
    __syncthreads();
    if (!tail_flag) return;
    __threadfence();                 // acquire: invalidate stale L1/L2 lines

    // scalar sums: 64 threads compute csum[c][b], c in {c1,c2,c3,c4}
    if (t < 64) {
        int c = t >> 4, b = t & 15;
        float s = 0.f;
        if (c < 2) {
            #pragma unroll
            for (int k = 0; k < 8; ++k) s += scal_part[(b * 8 + k) * 2 + c];
        } else {
            #pragma unroll
            for (int k = 0; k < 2; ++k) s += scal_part[(128 + b * 2 + k) * 2 + (c - 2)];
        }
        csum[c * BB + b] = s;
    }
    __syncthreads();

    // finalize 128 columns x 16 batches: 8 outputs / thread
    int jj = blockIdx.x * JC + (t & 127);
    int b0 = t >> 7;
    #pragma unroll
    for (int k = 0; k < 8; ++k) {
        int b = b0 + 2 * k;
        int idx = b * NN + jj;
        float s = 0.f;
        #pragma unroll
        for (int yy = 0; yy < YTOT; ++yy) s += part[(size_t)yy * (BB * NN) + idx];
        float x = out_X[idx];
        float c = s + 0.01f * (csum[0 * BB + b] + csum[2 * BB + b]) * x
                    - 0.012f * (csum[1 * BB + b] + csum[3 * BB + b]) * xpost[idx];
        out_V[idx] = 0.9f * V[idx] * (1.f - x) + c;
    }
}

extern "C" void kernel_launch(void* const* d_in, const int* in_sizes, int n_in,
                              void* d_out, int out_size, void* d_ws, size_t ws_size,
                              hipStream_t stream) {
    const float* FF       = (const float*)d_in[0];
    const float* V        = (const float*)d_in[1];
    const float* th       = (const float*)d_in[2];
    const float* Xbuf     = (const float*)d_in[3];
    const float* stp      = (const float*)d_in[4];
    const float* xpre_int = (const float*)d_in[5];
    const float* xpost    = (const float*)d_in[6];
    const float* xpre_ff  = (const float*)d_in[7];
    const float* Wint     = (const float*)d_in[8];
    const float* Wff      = (const float*)d_in[9];
    float* out = (float*)d_out;
    float* ws  = (float*)d_ws;

    float* T    = ws;                               // 32768 floats
    float* part = ws + BB * NN;                     // 40 * 32768 floats
    float* sp   = ws + BB * NN + YTOT * BB * NN;    // 320 floats
    unsigned int* cnt = (unsigned int*)(sp + 320);  // 16 uints

    snn_pre<<<(BB * NN + BB * NFF) / 256, 256, 0, stream>>>(
        FF, V, th, Xbuf, stp, xpre_int, xpre_ff, out, T, sp, cnt);

    snn_gemv<<<dim3(NN / JC, YTOT), 256, 0, stream>>>(
        Wint, Wff, T, FF, V, xpost, sp, out, out + BB * NN, part, cnt);
}

// Round 6
// 21.546 us; speedup vs baseline: 3.4812x; 3.4812x over previous
//
#include <hip/hip_runtime.h>

#define BB 16
#define NN 2048
#define NFF 512
#define DD 4

#define ROWS 64        // K-rows per gemv block (4 waves x 16 rows)
#define WR 16          // rows per wave
#define YINT 32        // 32*64 = 2048 Wint rows
#define YTOT 40        // + 8*64 = 512 Wff rows
#define JC   64        // columns per x-block (64 lanes x 1 col)

// ---------------- Kernel 1: elementwise pre-pass ----------------
// X = sigmoid((V-1-th)*5) -> out_X ; T[b,i] = sum_d Xd*(1+0.95*stp-0.3*Xd) -> ws
// Per-block partial sums for the 4 per-batch scalars:
//   blocks [0,128):   p0 = sum T*xpre_int, p1 = sum T*Xd0   (8 blocks/batch)
//   blocks [128,160): p0 = sum FF*xpre_ff, p1 = sum FF*FF   (2 blocks/batch)
__global__ __launch_bounds__(256) void snn_pre(
    const float* __restrict__ FF, const float* __restrict__ V,
    const float* __restrict__ th, const float* __restrict__ Xbuf,
    const float* __restrict__ stp, const float* __restrict__ xpre_int,
    const float* __restrict__ xpre_ff,
    float* __restrict__ out_X, float* __restrict__ T,
    float* __restrict__ scal_part)
{
    __shared__ float red[8];
    int idx = blockIdx.x * 256 + threadIdx.x;
    float p0, p1;
    if (idx < BB * NN) {
        float v = V[idx], t = th[idx];
        float x = 1.f / (1.f + expf(-(v - 1.f - t) * 5.f));
        out_X[idx] = x;
        float xd0 = Xbuf[idx];
        float acc = 0.f;
        #pragma unroll
        for (int d = 0; d < DD; ++d) {
            float xd = Xbuf[d * BB * NN + idx];
            float s  = stp[d * BB * NN + idx];
            acc += xd * (1.f + 0.95f * s - 0.3f * xd);
        }
        T[idx] = acc;
        p0 = acc * xpre_int[idx];
        p1 = acc * xd0;
    } else {
        int k = idx - BB * NN;
        float f = FF[k];
        p0 = f * xpre_ff[k];
        p1 = f * f;
    }
    #pragma unroll
    for (int o = 32; o; o >>= 1) { p0 += __shfl_xor(p0, o); p1 += __shfl_xor(p1, o); }
    int w = threadIdx.x >> 6;
    if ((threadIdx.x & 63) == 0) { red[w * 2] = p0; red[w * 2 + 1] = p1; }
    __syncthreads();
    if (threadIdx.x == 0) {
        scal_part[blockIdx.x * 2]     = red[0] + red[2] + red[4] + red[6];
        scal_part[blockIdx.x * 2 + 1] = red[1] + red[3] + red[5] + red[7];
    }
}

// ---------------- Kernel 2: split-K batched GEMV ----------------
// part[y][b][j] = sum_{i in y's 64 rows} OP[b,i] * W[i,j]
// y in [0,32): Wint / OP=T ; y in [32,40): Wff / OP=FF.
// 4 waves/block, 16 rows/wave, 1 col/lane: acc=16 VGPR, buf=16 VGPR so all
// 16 row-loads stay in flight; 1280 blocks -> ~20 waves/CU of TLP.
__global__ __launch_bounds__(256) void snn_gemv(
    const float* __restrict__ Wint, const float* __restrict__ Wff,
    const float* __restrict__ T, const float* __restrict__ FF,
    float* __restrict__ part)
{
    __shared__ float c_lds[ROWS * BB];           // 4 KB [row][b]
    __shared__ float red[2 * BB * 64];           // 8 KB [buf][b][lane]
    int y = blockIdx.y;
    const float* Wm; const float* OP; int i0, opstride;
    if (y < YINT) { Wm = Wint; OP = T;  i0 = y * ROWS;          opstride = NN;  }
    else          { Wm = Wff;  OP = FF; i0 = (y - YINT) * ROWS; opstride = NFF; }

    int t = threadIdx.x;
    #pragma unroll
    for (int k = 0; k < ROWS * BB / 256; ++k) {
        int e = k * 256 + t;
        int row = e >> 4, b = e & 15;
        c_lds[e] = OP[b * opstride + i0 + row];
    }
    __syncthreads();

    int w = t >> 6, l = t & 63;
    int j = blockIdx.x * JC + l;

    // issue ALL 16 row loads up front (16 x 4B outstanding per lane)
    const float* wp = Wm + (size_t)(i0 + w * WR) * NN + j;
    float buf[WR];
    #pragma unroll
    for (int r = 0; r < WR; ++r) buf[r] = wp[(size_t)r * NN];

    float acc[BB];
    #pragma unroll
    for (int b = 0; b < BB; ++b) acc[b] = 0.f;

    #pragma unroll
    for (int r = 0; r < WR; ++r) {
        const float4* cb = (const float4*)&c_lds[(w * WR + r) * BB];
        float4 c0 = cb[0], c1 = cb[1], c2 = cb[2], c3 = cb[3];
        float wv = buf[r];
        acc[0]  += c0.x * wv; acc[1]  += c0.y * wv; acc[2]  += c0.z * wv; acc[3]  += c0.w * wv;
        acc[4]  += c1.x * wv; acc[5]  += c1.y * wv; acc[6]  += c1.z * wv; acc[7]  += c1.w * wv;
        acc[8]  += c2.x * wv; acc[9]  += c2.y * wv; acc[10] += c2.z * wv; acc[11] += c2.w * wv;
        acc[12] += c3.x * wv; acc[13] += c3.y * wv; acc[14] += c3.z * wv; acc[15] += c3.w * wv;
    }

    // tree-reduce 4 waves: [b][lane] layout, stride-64 scalar b32, conflict-free
    if (w >= 2) {
        float* rb = &red[(w - 2) * BB * 64];
        #pragma unroll
        for (int b = 0; b < BB; ++b) rb[b * 64 + l] = acc[b];
    }
    __syncthreads();
    if (w < 2) {
        const float* rb = &red[w * BB * 64];
        #pragma unroll
        for (int b = 0; b < BB; ++b) acc[b] += rb[b * 64 + l];
    }
    __syncthreads();
    if (w == 1) {
        #pragma unroll
        for (int b = 0; b < BB; ++b) red[b * 64 + l] = acc[b];
    }
    __syncthreads();
    if (w == 0) {
        float* pp = part + (size_t)y * (BB * NN) + j;
        #pragma unroll
        for (int b = 0; b < BB; ++b)
            pp[(size_t)b * NN] = acc[b] + red[b * 64 + l];
    }
}

// ---------------- Kernel 3: reduce partials + finalize ----------------
__global__ __launch_bounds__(256) void snn_post(
    const float* __restrict__ V, const float* __restrict__ xpost,
    const float* __restrict__ part, const float* __restrict__ scal_part,
    const float* __restrict__ out_X, float* __restrict__ out_V)
{
    int idx = blockIdx.x * 256 + threadIdx.x;
    int b = idx >> 11;
    float c1 = 0.f, c2 = 0.f, c3 = 0.f, c4 = 0.f;
    #pragma unroll
    for (int k = 0; k < 8; ++k) {
        c1 += scal_part[(b * 8 + k) * 2];
        c2 += scal_part[(b * 8 + k) * 2 + 1];
    }
    #pragma unroll
    for (int k = 0; k < 2; ++k) {
        c3 += scal_part[(128 + b * 2 + k) * 2];
        c4 += scal_part[(128 + b * 2 + k) * 2 + 1];
    }
    float s = 0.f;
    #pragma unroll
    for (int yy = 0; yy < YTOT; ++yy) s += part[(size_t)yy * (BB * NN) + idx];
    float x = out_X[idx];
    float c = s + 0.01f * (c1 + c3) * x - 0.012f * (c2 + c4) * xpost[idx];
    out_V[idx] = 0.9f * V[idx] * (1.f - x) + c;
}

extern "C" void kernel_launch(void* const* d_in, const int* in_sizes, int n_in,
                              void* d_out, int out_size, void* d_ws, size_t ws_size,
                              hipStream_t stream) {
    const float* FF       = (const float*)d_in[0];
    const float* V        = (const float*)d_in[1];
    const float* th       = (const float*)d_in[2];
    const float* Xbuf     = (const float*)d_in[3];
    const float* stp      = (const float*)d_in[4];
    const float* xpre_int = (const float*)d_in[5];
    const float* xpost    = (const float*)d_in[6];
    const float* xpre_ff  = (const float*)d_in[7];
    const float* Wint     = (const float*)d_in[8];
    const float* Wff      = (const float*)d_in[9];
    float* out = (float*)d_out;
    float* ws  = (float*)d_ws;

    float* T    = ws;                               // 32768 floats
    float* part = ws + BB * NN;                     // 40 * 32768 floats
    float* sp   = ws + BB * NN + YTOT * BB * NN;    // 320 floats

    snn_pre<<<(BB * NN + BB * NFF) / 256, 256, 0, stream>>>(
        FF, V, th, Xbuf, stp, xpre_int, xpre_ff, out, T, sp);

    snn_gemv<<<dim3(NN / JC, YTOT), 256, 0, stream>>>(
        Wint, Wff, T, FF, part);

    snn_post<<<BB * NN / 256, 256, 0, stream>>>(
        V, xpost, part, sp, out, out + BB * NN);
}

// Round 7
// 18.803 us; speedup vs baseline: 3.9889x; 1.1459x over previous
//
#include <hip/hip_runtime.h>

#define BB 16
#define NN 2048
#define NFF 512
#define DD 4

#define ROWS 64        // K-rows per gemv block (4 waves x 16 rows)
#define WR 16          // rows per wave
#define YINT 32        // 32*64 = 2048 Wint rows
#define YTOT 40        // + 8*64 = 512 Wff rows
#define JC   256       // columns per x-block (64 lanes x 4 cols, float4)

// ---------------- Kernel 1: elementwise pre-pass ----------------
// X = sigmoid((V-1-th)*5) -> out_X ; T[b,i] = sum_d Xd*(1+0.95*stp-0.3*Xd) -> ws
// Per-block partial sums for the 4 per-batch scalars:
//   blocks [0,128):   p0 = sum T*xpre_int, p1 = sum T*Xd0   (8 blocks/batch)
//   blocks [128,160): p0 = sum FF*xpre_ff, p1 = sum FF*FF   (2 blocks/batch)
__global__ __launch_bounds__(256) void snn_pre(
    const float* __restrict__ FF, const float* __restrict__ V,
    const float* __restrict__ th, const float* __restrict__ Xbuf,
    const float* __restrict__ stp, const float* __restrict__ xpre_int,
    const float* __restrict__ xpre_ff,
    float* __restrict__ out_X, float* __restrict__ T,
    float* __restrict__ scal_part)
{
    __shared__ float red[8];
    int idx = blockIdx.x * 256 + threadIdx.x;
    float p0, p1;
    if (idx < BB * NN) {
        float v = V[idx], t = th[idx];
        float x = 1.f / (1.f + expf(-(v - 1.f - t) * 5.f));
        out_X[idx] = x;
        float xd0 = Xbuf[idx];
        float acc = 0.f;
        #pragma unroll
        for (int d = 0; d < DD; ++d) {
            float xd = Xbuf[d * BB * NN + idx];
            float s  = stp[d * BB * NN + idx];
            acc += xd * (1.f + 0.95f * s - 0.3f * xd);
        }
        T[idx] = acc;
        p0 = acc * xpre_int[idx];
        p1 = acc * xd0;
    } else {
        int k = idx - BB * NN;
        float f = FF[k];
        p0 = f * xpre_ff[k];
        p1 = f * f;
    }
    #pragma unroll
    for (int o = 32; o; o >>= 1) { p0 += __shfl_xor(p0, o); p1 += __shfl_xor(p1, o); }
    int w = threadIdx.x >> 6;
    if ((threadIdx.x & 63) == 0) { red[w * 2] = p0; red[w * 2 + 1] = p1; }
    __syncthreads();
    if (threadIdx.x == 0) {
        scal_part[blockIdx.x * 2]     = red[0] + red[2] + red[4] + red[6];
        scal_part[blockIdx.x * 2 + 1] = red[1] + red[3] + red[5] + red[7];
    }
}

// ---------------- Kernel 2: split-K batched GEMV, float4-wide ----------------
// part[y][b][j] = sum_{i in y's 64 rows} OP[b,i] * W[i,j]
// y in [0,32): Wint / OP=T ; y in [32,40): Wff / OP=FF.
// 4 waves/block, 16 rows/wave, 4 cols/lane via dwordx4 loads: 1 KB per load
// instruction (4x fewer vmem instrs than dword), 16 KB in flight per wave.
__global__ __launch_bounds__(256) void snn_gemv(
    const float* __restrict__ Wint, const float* __restrict__ Wff,
    const float* __restrict__ T, const float* __restrict__ FF,
    float* __restrict__ part)
{
    __shared__ float  c_lds[ROWS * BB];          // 4 KB  [row][b]
    __shared__ float4 red[2 * BB * 64];          // 32 KB [buf][b][lane]
    int y = blockIdx.y;
    const float* Wm; const float* OP; int i0, opstride;
    if (y < YINT) { Wm = Wint; OP = T;  i0 = y * ROWS;          opstride = NN;  }
    else          { Wm = Wff;  OP = FF; i0 = (y - YINT) * ROWS; opstride = NFF; }

    int t = threadIdx.x;
    #pragma unroll
    for (int k = 0; k < ROWS * BB / 256; ++k) {
        int e = k * 256 + t;
        int row = e >> 4, b = e & 15;
        c_lds[e] = OP[b * opstride + i0 + row];
    }
    __syncthreads();

    int w = t >> 6, l = t & 63;
    int j0 = blockIdx.x * JC + l * 4;

    // issue ALL 16 row loads up front (16 x 16B outstanding per lane)
    const float* wp = Wm + (size_t)(i0 + w * WR) * NN + j0;
    float4 buf[WR];
    #pragma unroll
    for (int r = 0; r < WR; ++r) buf[r] = *(const float4*)(wp + (size_t)r * NN);

    float4 acc[BB];
    #pragma unroll
    for (int b = 0; b < BB; ++b) acc[b] = make_float4(0.f, 0.f, 0.f, 0.f);

    #pragma unroll
    for (int r = 0; r < WR; ++r) {
        const float4* cb = (const float4*)&c_lds[(w * WR + r) * BB];
        float4 c0 = cb[0], c1 = cb[1], c2 = cb[2], c3 = cb[3];
        float4 wv = buf[r];
#define FMA4(b, cc) acc[b].x += (cc) * wv.x; acc[b].y += (cc) * wv.y; \
                    acc[b].z += (cc) * wv.z; acc[b].w += (cc) * wv.w;
        FMA4(0,  c0.x) FMA4(1,  c0.y) FMA4(2,  c0.z) FMA4(3,  c0.w)
        FMA4(4,  c1.x) FMA4(5,  c1.y) FMA4(6,  c1.z) FMA4(7,  c1.w)
        FMA4(8,  c2.x) FMA4(9,  c2.y) FMA4(10, c2.z) FMA4(11, c2.w)
        FMA4(12, c3.x) FMA4(13, c3.y) FMA4(14, c3.z) FMA4(15, c3.w)
#undef FMA4
    }

    // tree-reduce 4 waves: [b][lane] float4, contiguous b128 ops
    if (w >= 2) {
        float4* rb = &red[(w - 2) * BB * 64];
        #pragma unroll
        for (int b = 0; b < BB; ++b) rb[b * 64 + l] = acc[b];
    }
    __syncthreads();
    if (w < 2) {
        const float4* rb = &red[w * BB * 64];
        #pragma unroll
        for (int b = 0; b < BB; ++b) {
            float4 v = rb[b * 64 + l];
            acc[b].x += v.x; acc[b].y += v.y; acc[b].z += v.z; acc[b].w += v.w;
        }
    }
    __syncthreads();
    if (w == 1) {
        #pragma unroll
        for (int b = 0; b < BB; ++b) red[b * 64 + l] = acc[b];
    }
    __syncthreads();
    if (w == 0) {
        float* pp = part + (size_t)y * (BB * NN) + j0;
        #pragma unroll
        for (int b = 0; b < BB; ++b) {
            float4 v = red[b * 64 + l];
            acc[b].x += v.x; acc[b].y += v.y; acc[b].z += v.z; acc[b].w += v.w;
            *(float4*)(pp + (size_t)b * NN) = acc[b];
        }
    }
}

// ---------------- Kernel 3: reduce partials + finalize ----------------
__global__ __launch_bounds__(256) void snn_post(
    const float* __restrict__ V, const float* __restrict__ xpost,
    const float* __restrict__ part, const float* __restrict__ scal_part,
    const float* __restrict__ out_X, float* __restrict__ out_V)
{
    int idx = blockIdx.x * 256 + threadIdx.x;
    int b = idx >> 11;
    float c1 = 0.f, c2 = 0.f, c3 = 0.f, c4 = 0.f;
    #pragma unroll
    for (int k = 0; k < 8; ++k) {
        c1 += scal_part[(b * 8 + k) * 2];
        c2 += scal_part[(b * 8 + k) * 2 + 1];
    }
    #pragma unroll
    for (int k = 0; k < 2; ++k) {
        c3 += scal_part[(128 + b * 2 + k) * 2];
        c4 += scal_part[(128 + b * 2 + k) * 2 + 1];
    }
    float s = 0.f;
    #pragma unroll
    for (int yy = 0; yy < YTOT; ++yy) s += part[(size_t)yy * (BB * NN) + idx];
    float x = out_X[idx];
    float c = s + 0.01f * (c1 + c3) * x - 0.012f * (c2 + c4) * xpost[idx];
    out_V[idx] = 0.9f * V[idx] * (1.f - x) + c;
}

extern "C" void kernel_launch(void* const* d_in, const int* in_sizes, int n_in,
                              void* d_out, int out_size, void* d_ws, size_t ws_size,
                              hipStream_t stream) {
    const float* FF       = (const float*)d_in[0];
    const float* V        = (const float*)d_in[1];
    const float* th       = (const float*)d_in[2];
    const float* Xbuf     = (const float*)d_in[3];
    const float* stp      = (const float*)d_in[4];
    const float* xpre_int = (const float*)d_in[5];
    const float* xpost    = (const float*)d_in[6];
    const float* xpre_ff  = (const float*)d_in[7];
    const float* Wint     = (const float*)d_in[8];
    const float* Wff      = (const float*)d_in[9];
    float* out = (float*)d_out;
    float* ws  = (float*)d_ws;

    float* T    = ws;                               // 32768 floats
    float* part = ws + BB * NN;                     // 40 * 32768 floats
    float* sp   = ws + BB * NN + YTOT * BB * NN;    // 320 floats

    snn_pre<<<(BB * NN + BB * NFF) / 256, 256, 0, stream>>>(
        FF, V, th, Xbuf, stp, xpre_int, xpre_ff, out, T, sp);

    snn_gemv<<<dim3(NN / JC, YTOT), 256, 0, stream>>>(
        Wint, Wff, T, FF, part);

    snn_post<<<BB * NN / 256, 256, 0, stream>>>(
        V, xpost, part, sp, out, out + BB * NN);
}